// Round 8
// baseline (471.258 us; speedup 1.0000x reference)
//
#include <hip/hip_runtime.h>

typedef unsigned short u16;
typedef unsigned int u32;
typedef __bf16 bf16x8 __attribute__((ext_vector_type(8)));
typedef float f32x4 __attribute__((ext_vector_type(4)));
typedef u32 u32x4 __attribute__((ext_vector_type(4)));

__device__ __forceinline__ float bf2f(u16 u) {
    union { u32 u; float f; } x; x.u = ((u32)u) << 16; return x.f;
}
__device__ __forceinline__ u16 f2bf(float f) {
    union { float f; u32 u; } x; x.f = f;
    u32 r = x.u + 0x7fffu + ((x.u >> 16) & 1u);
    return (u16)(r >> 16);
}
__device__ __forceinline__ void unpack8(uint4 d, float* f) {
    f[0] = bf2f((u16)(d.x & 0xffffu)); f[1] = bf2f((u16)(d.x >> 16));
    f[2] = bf2f((u16)(d.y & 0xffffu)); f[3] = bf2f((u16)(d.y >> 16));
    f[4] = bf2f((u16)(d.z & 0xffffu)); f[5] = bf2f((u16)(d.z >> 16));
    f[6] = bf2f((u16)(d.w & 0xffffu)); f[7] = bf2f((u16)(d.w >> 16));
}
// pack 2 f32 -> u32 of 2 bf16 (RNE), single instruction; low half = first arg
__device__ __forceinline__ u32 cvtpk_bf16(float lo, float hi) {
    u32 r;
    asm("v_cvt_pk_bf16_f32 %0, %1, %2" : "=v"(r) : "v"(lo), "v"(hi));
    return r;
}

// ---- dtype sniffing: fp32 data read as bf16 halfwords has wild exponents ----
__global__ __launch_bounds__(256) void k_flag(const void* __restrict__ x, int* __restrict__ flag) {
    const u16* p = (const u16*)x;
    const int t = threadIdx.x;
    float mx = 0.f;
    for (int i = t; i < 4096; i += 256) {
        float v = fabsf(bf2f(p[i]));
        if (!(v < 1e30f)) v = 1e30f;  // NaN/Inf -> big
        mx = fmaxf(mx, v);
    }
    __shared__ float red[256];
    red[t] = mx; __syncthreads();
    for (int s = 128; s > 0; s >>= 1) {
        if (t < s) red[t] = fmaxf(red[t], red[t + s]);
        __syncthreads();
    }
    if (t == 0) *flag = (red[0] > 1e6f) ? 1 : 0;  // 1 = fp32, 0 = bf16
}

// -------- weight transpose+convert (+optional scale): Wt[n*K+k] = bf16(W[k*N+n]*s) --------
__global__ void k_tr(const void* __restrict__ W, u16* __restrict__ Wt, int K, int N,
                     const int* __restrict__ flagp, float scale) {
    const int flag = *flagp;
    int idx = blockIdx.x * 256 + threadIdx.x;
    if (idx < K * N) {
        int k = idx / N, n = idx - k * N;
        float f = flag ? ((const float*)W)[idx] : bf2f(((const u16*)W)[idx]);
        Wt[n * K + k] = f2bf(f * scale);
    }
}

// ---------------- LayerNorm over D=256, one wave per local row ----------------
__global__ __launch_bounds__(256) void k_ln(
        const void* __restrict__ x, const void* __restrict__ g,
        const void* __restrict__ b, u16* __restrict__ xn,
        int so, int si, int base, const int* __restrict__ flagp, int xmode) {
    const int flag = *flagp;
    const int xf = xmode ? flag : 0;
    const int wave = threadIdx.x >> 6, lane = threadIdx.x & 63;
    const int r = blockIdx.x * 4 + wave;
    const int in_row = (r >> 7) * so + (r & 127) * si + base;
    const size_t off = (size_t)in_row * 256 + lane * 4;
    float v[4];
    if (xf) {
        float4 d = *(const float4*)((const float*)x + off);
        v[0] = d.x; v[1] = d.y; v[2] = d.z; v[3] = d.w;
    } else {
        uint2 d = *(const uint2*)((const u16*)x + off);
        v[0] = bf2f((u16)(d.x & 0xffffu)); v[1] = bf2f((u16)(d.x >> 16));
        v[2] = bf2f((u16)(d.y & 0xffffu)); v[3] = bf2f((u16)(d.y >> 16));
    }
    float s = v[0] + v[1] + v[2] + v[3];
    #pragma unroll
    for (int o2 = 32; o2 > 0; o2 >>= 1) s += __shfl_xor(s, o2, 64);
    float mu = s * (1.f / 256.f);
    float vs = 0.f;
    #pragma unroll
    for (int e = 0; e < 4; e++) { float t = v[e] - mu; vs += t * t; }
    #pragma unroll
    for (int o2 = 32; o2 > 0; o2 >>= 1) vs += __shfl_xor(vs, o2, 64);
    float rr = rsqrtf(vs * (1.f / 256.f) + 1e-5f);
    float gf[4], bf_[4];
    if (flag) {
        float4 gg = *(const float4*)((const float*)g + lane * 4);
        float4 bb = *(const float4*)((const float*)b + lane * 4);
        gf[0] = gg.x; gf[1] = gg.y; gf[2] = gg.z; gf[3] = gg.w;
        bf_[0] = bb.x; bf_[1] = bb.y; bf_[2] = bb.z; bf_[3] = bb.w;
    } else {
        uint2 gg = *(const uint2*)((const u16*)g + lane * 4);
        uint2 bb = *(const uint2*)((const u16*)b + lane * 4);
        gf[0] = bf2f((u16)(gg.x & 0xffffu)); gf[1] = bf2f((u16)(gg.x >> 16));
        gf[2] = bf2f((u16)(gg.y & 0xffffu)); gf[3] = bf2f((u16)(gg.y >> 16));
        bf_[0] = bf2f((u16)(bb.x & 0xffffu)); bf_[1] = bf2f((u16)(bb.x >> 16));
        bf_[2] = bf2f((u16)(bb.y & 0xffffu)); bf_[3] = bf2f((u16)(bb.y >> 16));
    }
    u16 o[4];
    #pragma unroll
    for (int e = 0; e < 4; e++) o[e] = f2bf((v[e] - mu) * rr * gf[e] + bf_[e]);
    uint2 ov;
    ov.x = (u32)o[0] | ((u32)o[1] << 16);
    ov.y = (u32)o[2] | ((u32)o[3] << 16);
    *(uint2*)(xn + (size_t)r * 256 + lane * 4) = ov;
}

// ------------- pairwise bias: bias[h][i][j] = LOG2E * sum_d pw[i][j][d]*we[d][h] -------------
// (log2-domain: attn kernel computes p = exp2(score) directly)
__global__ __launch_bounds__(256) void k_bias(
        const void* __restrict__ pw, const void* __restrict__ we,
        float* __restrict__ bias, const int* __restrict__ flagp) {
    const int flag = *flagp;
    __shared__ float swe[2048];  // [256][8] fp32
    for (int t = threadIdx.x; t < 2048; t += 256)
        swe[t] = flag ? ((const float*)we)[t] : bf2f(((const u16*)we)[t]);
    __syncthreads();
    const int i = blockIdx.x, j = threadIdx.x;
    const size_t rowoff = ((size_t)i * 256 + j) * 256;
    float acc[8] = {0.f, 0.f, 0.f, 0.f, 0.f, 0.f, 0.f, 0.f};
    for (int d0 = 0; d0 < 256; d0 += 8) {
        float f[8];
        if (flag) {
            const float* p32 = (const float*)pw + rowoff + d0;
            float4 a = *(const float4*)p32;
            float4 b = *(const float4*)(p32 + 4);
            f[0] = a.x; f[1] = a.y; f[2] = a.z; f[3] = a.w;
            f[4] = b.x; f[5] = b.y; f[6] = b.z; f[7] = b.w;
        } else {
            unpack8(*(const uint4*)((const u16*)pw + rowoff + d0), f);
        }
        #pragma unroll
        for (int e = 0; e < 8; e++) {
            const float* w = swe + (d0 + e) * 8;
            #pragma unroll
            for (int hh = 0; hh < 8; hh++) acc[hh] += f[e] * w[hh];
        }
    }
    #pragma unroll
    for (int hh = 0; hh < 8; hh++)
        bias[((size_t)hh * 256 + i) * 256 + j] = acc[hh] * 1.4426950408889634f;
}

// ---------------- MFMA GEMM: C[M,N] = A[M,256] @ Bt[N,256]^T ----------------
template<bool EPI, bool PERM, bool RESF, bool OUTF>
__global__ __launch_bounds__(256, 3) void k_gemm(
        const u16* __restrict__ A, const u16* __restrict__ Bt, void* __restrict__ C,
        size_t c_off, int N, const void* __restrict__ bias,
        const void* __restrict__ res, size_t res_off, int n0,
        const int* __restrict__ flagp) {
    constexpr int K = 256;
    const int flag = *flagp;
    __shared__ u16 sA[128 * 40];
    __shared__ u16 sB[128 * 40];
    const int tid = threadIdx.x;
    const int bm = blockIdx.x * 128, bn = blockIdx.y * 128;
    const int wave = tid >> 6, lane = tid & 63;
    const int wm = (wave >> 1) * 64, wn = (wave & 1) * 64;
    const int lr = lane & 15, lq = lane >> 4;
    f32x4 acc[4][4];
    #pragma unroll
    for (int a = 0; a < 4; a++)
        #pragma unroll
        for (int b2 = 0; b2 < 4; b2++) {
            acc[a][b2][0] = 0.f; acc[a][b2][1] = 0.f;
            acc[a][b2][2] = 0.f; acc[a][b2][3] = 0.f;
        }
    for (int k0 = 0; k0 < K; k0 += 32) {
        for (int c = tid; c < 512; c += 256) {
            int r = c >> 2, cc = (c & 3) << 3;
            *(uint4*)(sA + r * 40 + cc) = *(const uint4*)(A + (size_t)(bm + r) * K + k0 + cc);
            *(uint4*)(sB + r * 40 + cc) = *(const uint4*)(Bt + (size_t)(bn + r) * K + k0 + cc);
        }
        __syncthreads();
        bf16x8 af[4], bfr[4];
        #pragma unroll
        for (int t = 0; t < 4; t++) {
            af[t]  = *(const bf16x8*)(sA + (wm + t * 16 + lr) * 40 + lq * 8);
            bfr[t] = *(const bf16x8*)(sB + (wn + t * 16 + lr) * 40 + lq * 8);
        }
        #pragma unroll
        for (int mt = 0; mt < 4; mt++)
            #pragma unroll
            for (int nt = 0; nt < 4; nt++)
                acc[mt][nt] = __builtin_amdgcn_mfma_f32_16x16x32_bf16(
                        af[mt], bfr[nt], acc[mt][nt], 0, 0, 0);
        __syncthreads();
    }
    #pragma unroll
    for (int mt = 0; mt < 4; mt++)
        #pragma unroll
        for (int nt = 0; nt < 4; nt++)
            #pragma unroll
            for (int r = 0; r < 4; r++) {
                int row = bm + wm + mt * 16 + lq * 4 + r;
                int orow = PERM ? ((row & 127) * 256 + n0 + (row >> 7)) : row;
                int col = bn + wn + nt * 16 + lr;
                float v = acc[mt][nt][r];
                if (EPI) {
                    float bv = flag ? ((const float*)bias)[col] : bf2f(((const u16*)bias)[col]);
                    size_t ri = res_off + (size_t)orow * N + col;
                    float rv = (RESF && flag) ? ((const float*)res)[ri]
                                              : bf2f(((const u16*)res)[ri]);
                    v += bv + rv;
                }
                size_t ci = c_off + (size_t)orow * N + col;
                if (OUTF && flag) ((float*)C)[ci] = v;
                else ((u16*)C)[ci] = f2bf(v);
            }
}

// ---------------- MFMA flash attention (transposed-S) + output gating ----------------
// BASE = R6/R7 (PASSED, 411.6us, row-attn 61us). R8's ONLY change: NO K LDS staging.
// The S-MFMA A-fragment is lane(lr,lq) <- 16 contiguous bytes of K row rk at column
// lq*8 -- read DIRECTLY from global P (same bytes the old sk staging+swizzle served;
// swizzle algebra: staged slot lq^sw held chunk lq). Per-qt K re-reads (4x 16KB/block)
// are L2 hits (16KB footprint); HBM bytes unchanged. LDS 34.3KB -> 17.9KB (row) /
// 9.2KB (col) -> 8 blocks/CU, 32 waves = 2x resident waves = 2x memory-level
// parallelism. R7 evidence this kernel runs AT its effective BW (1.75TB/s, latency-
// limited): more waves -> more outstanding loads -> higher effective BW.
// (R7 waves_per_eu(4,4) attribute was a no-op -- VGPR stayed 64, no spill existed;
// excess WRITE is attn_c partial-line write-amplification, ~2us, not worth chasing.)
// Everything else identical: p = exp2(score) no-max softmax, cvt_pk + permlane32_swap
// + shfl_xor(16) P redistribution (proven R3/R6), batch-4 S-tiles.
template<bool HB, int L>
__global__ __launch_bounds__(L, 4) void k_attn_mfma(
        const u16* __restrict__ P, const float* __restrict__ bias,
        const int* __restrict__ mask, const void* __restrict__ bg,
        u16* __restrict__ out, int bstride, int mi_s, int mb_s, int m_base,
        const int* __restrict__ flagp) {
    constexpr int KT = L / 16;        // key tiles
    constexpr int NB = KT / 4;        // batches of 4 tiles (64 keys)
    constexpr int VROW = L + 8;       // svt row stride (halfwords)
    __shared__ u16 svt[32 * VROW];    // V^T [32][L]
    __shared__ float amk[L];          // additive key mask: 0 valid / -1e9 masked
    const int flag = *flagp;
    const int h = blockIdx.x, b = blockIdx.y;
    const int tid = threadIdx.x;
    constexpr float LOG2E = 1.4426950408889634f;

    // ---- stage V^T, additive mask (K is NOT staged -- read from global per tile) ----
    {
        const size_t prow = (size_t)(b * bstride + tid) * 1024 + h * 32;
        const u16* vp = P + prow + 512;
        #pragma unroll
        for (int c = 0; c < 4; c++) {
            uint4 d = *(const uint4*)(vp + c * 8);
            u16 hw[8];
            hw[0] = (u16)(d.x & 0xffffu); hw[1] = (u16)(d.x >> 16);
            hw[2] = (u16)(d.y & 0xffffu); hw[3] = (u16)(d.y >> 16);
            hw[4] = (u16)(d.z & 0xffffu); hw[5] = (u16)(d.z >> 16);
            hw[6] = (u16)(d.w & 0xffffu); hw[7] = (u16)(d.w >> 16);
            #pragma unroll
            for (int e = 0; e < 8; e++)
                svt[(c * 8 + e) * VROW + tid] = hw[e];
        }
        amk[tid] = (mask[tid * mi_s + b * mb_s + m_base] != 0) ? 0.f : -1e9f;
    }
    __syncthreads();

    const int wave = tid >> 6, lane = tid & 63;
    const int lq = lane >> 4, lr = lane & 15;
    const bool hi_lq = (lq & 1) != 0;
    const int qbase = wave * 64;

    // K A-fragment base: lane reads row (kt*16+lr), 16B at column lq*8 of the K slice
    const u16* kfr = P + (size_t)(b * bstride + lr) * 1024 + 256 + h * 32 + lq * 8;

    // Q fragments: register layout identical for A and B operands (read [lr][lq*8..+8])
    bf16x8 qf[4];
    #pragma unroll
    for (int qt = 0; qt < 4; qt++) {
        const size_t qrow = (size_t)(b * bstride + qbase + qt * 16 + lr) * 1024 + h * 32;
        qf[qt] = *(const bf16x8*)(P + qrow + lq * 8);
    }
    float bgv[2];
    #pragma unroll
    for (int dt = 0; dt < 2; dt++)
        bgv[dt] = flag ? ((const float*)bg)[h * 32 + dt * 16 + lr]
                       : bf2f(((const u16*)bg)[h * 32 + dt * 16 + lr]);

    const f32x4 zero = {0.f, 0.f, 0.f, 0.f};
    #pragma unroll
    for (int qt = 0; qt < 4; qt++) {
        const float qv = amk[qbase + qt * 16 + lr];   // 0 = valid query, -1e9 = masked
        const bool qok = (qv == 0.f);
        const float* bp = HB ? (bias + ((size_t)(h * 256 + qbase + qt * 16 + lr)) * 256)
                             : nullptr;
        // gate prefetch (consumed only in the epilogue)
        const u16* gbase = P + (size_t)(b * bstride + qbase + qt * 16 + lq * 4) * 1024
                           + 768 + h * 32 + lr;
        u16 gpre[8];
        #pragma unroll
        for (int r = 0; r < 4; r++) {
            gpre[r * 2 + 0] = gbase[r * 1024];
            gpre[r * 2 + 1] = gbase[r * 1024 + 16];
        }
        float lsum = 0.f;
        f32x4 o0 = zero, o1 = zero;
        #pragma unroll
        for (int b4 = 0; b4 < NB; b4++) {
            // ---- batched bias loads (overlap the MFMA burst) ----
            float4 bias4[4];
            if (HB) {
                #pragma unroll
                for (int t = 0; t < 4; t++)
                    bias4[t] = *(const float4*)(bp + (b4 * 4 + t) * 16 + lq * 4);
            }
            // ---- S^T: 4 tiles of 16 keys, K A-frags straight from global (L2-hot) ----
            f32x4 s4[4];
            __builtin_amdgcn_s_setprio(1);
            #pragma unroll
            for (int t = 0; t < 4; t++) {
                bf16x8 ak = *(const bf16x8*)(kfr + (size_t)((b4 * 4 + t) * 16) * 1024);
                s4[t] = __builtin_amdgcn_mfma_f32_16x16x32_bf16(ak, qf[qt], zero, 0, 0, 0);
            }
            __builtin_amdgcn_s_setprio(0);
            // ---- per 32-key chunk: exp2 -> in-register redistribute -> PV MFMA ----
            #pragma unroll
            for (int cc = 0; cc < 2; cc++) {
                const int ch = b4 * 2 + cc;           // global chunk of 32 keys
                float p0[4], p1[4];
                #pragma unroll
                for (int t2 = 0; t2 < 2; t2++) {
                    const int t = 2 * cc + t2;
                    const int kt = b4 * 4 + t;
                    const float4 ka = *(const float4*)(amk + kt * 16 + lq * 4);
                    const float* kap = (const float*)&ka;
                    float* pp = t2 ? p1 : p0;
                    #pragma unroll
                    for (int r = 0; r < 4; r++) {
                        float v = s4[t][r] + kap[r];
                        if (HB) v += ((const float*)&bias4[t])[r];
                        v = qok ? fminf(v, 80.f) : 0.f;   // masked query: p=1 uniform
                        pp[r] = __builtin_amdgcn_exp2f(v);
                        lsum += pp[r];
                    }
                }
                // pack + 4-lane lq-permute, all in registers (PROVEN in R3)
                u32 y0 = cvtpk_bf16(p0[0], p0[1]);   // A of tile t2=0 (keys lq*4+0,1)
                u32 z0 = cvtpk_bf16(p0[2], p0[3]);   // B of tile t2=0 (keys lq*4+2,3)
                u32 y1 = cvtpk_bf16(p1[0], p1[1]);   // A of tile t2=1
                u32 z1 = cvtpk_bf16(p1[2], p1[3]);   // B of tile t2=1
                // half-swap: after this Y0 = A_{lq>>1}(lq&1), Y1 = A_{lq>>1}((lq&1)+2)
                asm("v_permlane32_swap_b32 %0, %1" : "+v"(y0), "+v"(y1));
                asm("v_permlane32_swap_b32 %0, %1" : "+v"(z0), "+v"(z1));
                const u32 sy0 = (u32)__shfl_xor((int)y0, 16, 64);
                const u32 sy1 = (u32)__shfl_xor((int)y1, 16, 64);
                const u32 sz0 = (u32)__shfl_xor((int)z0, 16, 64);
                const u32 sz1 = (u32)__shfl_xor((int)z1, 16, 64);
                u32x4 pu;
                pu.x = hi_lq ? sy1 : y0;   // keys 8lq+0,1
                pu.y = hi_lq ? sz1 : z0;   // keys 8lq+2,3
                pu.z = hi_lq ? y1 : sy0;   // keys 8lq+4,5
                pu.w = hi_lq ? z1 : sz0;   // keys 8lq+6,7
                const bf16x8 pa = __builtin_bit_cast(bf16x8, pu);
                bf16x8 vb0 = *(const bf16x8*)(svt + (size_t)lr * VROW + ch * 32 + lq * 8);
                bf16x8 vb1 = *(const bf16x8*)(svt + (size_t)(16 + lr) * VROW + ch * 32 + lq * 8);
                o0 = __builtin_amdgcn_mfma_f32_16x16x32_bf16(pa, vb0, o0, 0, 0, 0);
                o1 = __builtin_amdgcn_mfma_f32_16x16x32_bf16(pa, vb1, o1, 0, 0, 0);
            }
        }
        lsum += __shfl_xor(lsum, 16, 64);
        lsum += __shfl_xor(lsum, 32, 64);
        // ---- epilogue: 1/l, gate sigmoid, store (O rows = queries lq*4+r) ----
        #pragma unroll
        for (int r = 0; r < 4; r++) {
            const float lq_l = __shfl(lsum, (lane & 48) | (lq * 4 + r), 64);
            const float inv = __builtin_amdgcn_rcpf(lq_l);
            const size_t row = (size_t)(b * bstride + qbase + qt * 16 + lq * 4 + r);
            u16* op = out + row * 256 + h * 32;
            #pragma unroll
            for (int dt = 0; dt < 2; dt++) {
                const float ov = (dt ? o1[r] : o0[r]) * inv;
                const float g = bf2f(gpre[r * 2 + dt]) + bgv[dt];
                const float sig = __builtin_amdgcn_rcpf(1.f + __builtin_amdgcn_exp2f(-g * LOG2E));
                op[dt * 16 + lr] = f2bf(ov * sig);
            }
        }
    }
}

extern "C" void kernel_launch(void* const* d_in, const int* in_sizes, int n_in,
                              void* d_out, int out_size, void* d_ws, size_t ws_size,
                              hipStream_t stream) {
    (void)in_sizes; (void)n_in; (void)out_size;
    const void* x        = d_in[0];
    const void* pw       = d_in[1];
    const int*  mask     = (const int*)d_in[2];
    const void* row_ln_g = d_in[3];
    const void* row_ln_b = d_in[4];
    const void* row_wq   = d_in[5];
    const void* row_wkv  = d_in[6];
    const void* row_wg   = d_in[7];
    const void* row_bg   = d_in[8];
    const void* row_wo   = d_in[9];
    const void* row_bo   = d_in[10];
    const void* row_we   = d_in[11];
    const void* col_ln_g = d_in[12];
    const void* col_ln_b = d_in[13];
    const void* col_wq   = d_in[14];
    const void* col_wkv  = d_in[15];
    const void* col_wg   = d_in[16];
    const void* col_bg   = d_in[17];
    const void* col_wo   = d_in[18];
    const void* col_bo   = d_in[19];

    // 1/sqrt(32) * log2(e), folded into wq -> attn computes p = exp2(score)
    const float QSCALE = 0.17677669529663687f * 1.4426950408889634f;

    // choose chunking from ws_size (host-side, capture-stable):
    const int nc = (ws_size >= 120193536u) ? 1 : 8;
    const int rows = 32768 / nc;          // rows per chunk

    char* ws = (char*)d_ws;
    size_t off = 0;
    int*   flagp  = (int*)(ws + off);  off += 512;
    u16*   Wt     = (u16*)(ws + off);  off += 524288;      // [1024][256] bf16
    u16*   WoT    = (u16*)(ws + off);  off += 131072;      // [256][256] bf16
    float* biasb  = (float*)(ws + off); off += 2097152;    // [8][256][256] fp32
    u16*   xn_c   = (u16*)(ws + off);  off += (size_t)rows * 512;   // bf16
    u16*   attn_c = (u16*)(ws + off);  off += (size_t)rows * 512;   // bf16
    u16*   P_c    = (u16*)(ws + off);  off += (size_t)rows * 2048;  // bf16
    u16*   x1     = (u16*)(ws + off);  off += 16777216;    // [32768][256] bf16

    k_flag<<<1, 256, 0, stream>>>(x, flagp);

    // ---------------- stage 1: row attention (x1 in ws, bf16) ----------------
    k_tr<<<256, 256, 0, stream>>>(row_wq,  Wt,             256, 256, flagp, QSCALE);
    k_tr<<<512, 256, 0, stream>>>(row_wkv, Wt + 256 * 256, 256, 512, flagp, 1.f);
    k_tr<<<256, 256, 0, stream>>>(row_wg,  Wt + 768 * 256, 256, 256, flagp, 1.f);
    k_tr<<<256, 256, 0, stream>>>(row_wo,  WoT,            256, 256, flagp, 1.f);
    k_bias<<<256, 256, 0, stream>>>(pw, row_we, biasb, flagp);
    for (int c = 0; c < nc; c++) {
        const int s0 = c * (128 / nc);    // first MSA row of chunk
        k_ln<<<rows / 4, 256, 0, stream>>>(x, row_ln_g, row_ln_b, xn_c,
                                           128, 1, s0 * 256, flagp, 1);
        k_gemm<false, false, false, false><<<dim3(rows / 128, 8), 256, 0, stream>>>(
                xn_c, Wt, P_c, 0, 1024, nullptr, nullptr, 0, 0, flagp);
        k_attn_mfma<true, 256><<<dim3(8, 128 / nc), 256, 0, stream>>>(
                P_c, biasb, mask, row_bg, attn_c, 256, 1, 256, s0 * 256, flagp);
        k_gemm<true, false, true, false><<<dim3(rows / 128, 2), 256, 0, stream>>>(
                attn_c, WoT, x1, (size_t)s0 * 65536, 256,
                row_bo, x, (size_t)s0 * 65536, 0, flagp);
    }

    // ---------------- stage 2: column attention (reads x1 bf16, writes d_out) ----------------
    k_tr<<<256, 256, 0, stream>>>(col_wq,  Wt,             256, 256, flagp, QSCALE);
    k_tr<<<512, 256, 0, stream>>>(col_wkv, Wt + 256 * 256, 256, 512, flagp, 1.f);
    k_tr<<<256, 256, 0, stream>>>(col_wg,  Wt + 768 * 256, 256, 256, flagp, 1.f);
    k_tr<<<256, 256, 0, stream>>>(col_wo,  WoT,            256, 256, flagp, 1.f);
    for (int c = 0; c < nc; c++) {
        const int n0 = c * (256 / nc);    // first residue column of chunk
        k_ln<<<rows / 4, 256, 0, stream>>>(x1, col_ln_g, col_ln_b, xn_c,
                                           1, 256, n0, flagp, 0);
        k_gemm<false, false, false, false><<<dim3(rows / 128, 8), 256, 0, stream>>>(
                xn_c, Wt, P_c, 0, 1024, nullptr, nullptr, 0, 0, flagp);
        k_attn_mfma<false, 128><<<dim3(8, 256 / nc), 128, 0, stream>>>(
                P_c, nullptr, mask, col_bg, attn_c, 128, 256, 1, n0, flagp);
        k_gemm<true, true, false, true><<<dim3(rows / 128, 2), 256, 0, stream>>>(
                attn_c, WoT, d_out, 0, 256, col_bo, x1, 0, n0, flagp);
    }
}

// Round 9
// 421.108 us; speedup vs baseline: 1.1191x; 1.1191x over previous
//
#include <hip/hip_runtime.h>

typedef unsigned short u16;
typedef unsigned int u32;
typedef __bf16 bf16x8 __attribute__((ext_vector_type(8)));
typedef float f32x4 __attribute__((ext_vector_type(4)));
typedef u32 u32x4 __attribute__((ext_vector_type(4)));

__device__ __forceinline__ float bf2f(u16 u) {
    union { u32 u; float f; } x; x.u = ((u32)u) << 16; return x.f;
}
__device__ __forceinline__ u16 f2bf(float f) {
    union { float f; u32 u; } x; x.f = f;
    u32 r = x.u + 0x7fffu + ((x.u >> 16) & 1u);
    return (u16)(r >> 16);
}
__device__ __forceinline__ void unpack8(uint4 d, float* f) {
    f[0] = bf2f((u16)(d.x & 0xffffu)); f[1] = bf2f((u16)(d.x >> 16));
    f[2] = bf2f((u16)(d.y & 0xffffu)); f[3] = bf2f((u16)(d.y >> 16));
    f[4] = bf2f((u16)(d.z & 0xffffu)); f[5] = bf2f((u16)(d.z >> 16));
    f[6] = bf2f((u16)(d.w & 0xffffu)); f[7] = bf2f((u16)(d.w >> 16));
}
// pack 2 f32 -> u32 of 2 bf16 (RNE), single instruction; low half = first arg
__device__ __forceinline__ u32 cvtpk_bf16(float lo, float hi) {
    u32 r;
    asm("v_cvt_pk_bf16_f32 %0, %1, %2" : "=v"(r) : "v"(lo), "v"(hi));
    return r;
}

// ---- dtype sniffing: fp32 data read as bf16 halfwords has wild exponents ----
__global__ __launch_bounds__(256) void k_flag(const void* __restrict__ x, int* __restrict__ flag) {
    const u16* p = (const u16*)x;
    const int t = threadIdx.x;
    float mx = 0.f;
    for (int i = t; i < 4096; i += 256) {
        float v = fabsf(bf2f(p[i]));
        if (!(v < 1e30f)) v = 1e30f;  // NaN/Inf -> big
        mx = fmaxf(mx, v);
    }
    __shared__ float red[256];
    red[t] = mx; __syncthreads();
    for (int s = 128; s > 0; s >>= 1) {
        if (t < s) red[t] = fmaxf(red[t], red[t + s]);
        __syncthreads();
    }
    if (t == 0) *flag = (red[0] > 1e6f) ? 1 : 0;  // 1 = fp32, 0 = bf16
}

// -------- fused weight transpose+convert for one attention stage --------
// Segments (1280 blocks): [0,256) wq*qscale -> Wt, [256,768) wkv -> Wt+65536,
// [768,1024) wg -> Wt+196608, [1024,1280) wo -> WoT. All K=256; Wt[n*256+k].
__global__ __launch_bounds__(256) void k_tr4(
        const void* __restrict__ W0, const void* __restrict__ W1,
        const void* __restrict__ W2, const void* __restrict__ W3,
        u16* __restrict__ Wt, u16* __restrict__ WoT,
        const int* __restrict__ flagp, float qscale) {
    const int flag = *flagp;
    const int blk = blockIdx.x;
    const void* W; u16* dst; int N; float scale = 1.f; int base;
    if (blk < 256)       { W = W0; dst = Wt;          N = 256; scale = qscale; base = 0; }
    else if (blk < 768)  { W = W1; dst = Wt + 65536;  N = 512; base = 256; }
    else if (blk < 1024) { W = W2; dst = Wt + 196608; N = 256; base = 768; }
    else                 { W = W3; dst = WoT;         N = 256; base = 1024; }
    const int idx = (blk - base) * 256 + threadIdx.x;
    const int k = idx / N, n = idx - k * N;
    float f = flag ? ((const float*)W)[idx] : bf2f(((const u16*)W)[idx]);
    dst[n * 256 + k] = f2bf(f * scale);
}

// ---------------- LayerNorm over D=256, one wave per local row ----------------
__global__ __launch_bounds__(256) void k_ln(
        const void* __restrict__ x, const void* __restrict__ g,
        const void* __restrict__ b, u16* __restrict__ xn,
        int so, int si, int base, const int* __restrict__ flagp, int xmode) {
    const int flag = *flagp;
    const int xf = xmode ? flag : 0;
    const int wave = threadIdx.x >> 6, lane = threadIdx.x & 63;
    const int r = blockIdx.x * 4 + wave;
    const int in_row = (r >> 7) * so + (r & 127) * si + base;
    const size_t off = (size_t)in_row * 256 + lane * 4;
    float v[4];
    if (xf) {
        float4 d = *(const float4*)((const float*)x + off);
        v[0] = d.x; v[1] = d.y; v[2] = d.z; v[3] = d.w;
    } else {
        uint2 d = *(const uint2*)((const u16*)x + off);
        v[0] = bf2f((u16)(d.x & 0xffffu)); v[1] = bf2f((u16)(d.x >> 16));
        v[2] = bf2f((u16)(d.y & 0xffffu)); v[3] = bf2f((u16)(d.y >> 16));
    }
    float s = v[0] + v[1] + v[2] + v[3];
    #pragma unroll
    for (int o2 = 32; o2 > 0; o2 >>= 1) s += __shfl_xor(s, o2, 64);
    float mu = s * (1.f / 256.f);
    float vs = 0.f;
    #pragma unroll
    for (int e = 0; e < 4; e++) { float t = v[e] - mu; vs += t * t; }
    #pragma unroll
    for (int o2 = 32; o2 > 0; o2 >>= 1) vs += __shfl_xor(vs, o2, 64);
    float rr = rsqrtf(vs * (1.f / 256.f) + 1e-5f);
    float gf[4], bf_[4];
    if (flag) {
        float4 gg = *(const float4*)((const float*)g + lane * 4);
        float4 bb = *(const float4*)((const float*)b + lane * 4);
        gf[0] = gg.x; gf[1] = gg.y; gf[2] = gg.z; gf[3] = gg.w;
        bf_[0] = bb.x; bf_[1] = bb.y; bf_[2] = bb.z; bf_[3] = bb.w;
    } else {
        uint2 gg = *(const uint2*)((const u16*)g + lane * 4);
        uint2 bb = *(const uint2*)((const u16*)b + lane * 4);
        gf[0] = bf2f((u16)(gg.x & 0xffffu)); gf[1] = bf2f((u16)(gg.x >> 16));
        gf[2] = bf2f((u16)(gg.y & 0xffffu)); gf[3] = bf2f((u16)(gg.y >> 16));
        bf_[0] = bf2f((u16)(bb.x & 0xffffu)); bf_[1] = bf2f((u16)(bb.x >> 16));
        bf_[2] = bf2f((u16)(bb.y & 0xffffu)); bf_[3] = bf2f((u16)(bb.y >> 16));
    }
    u16 o[4];
    #pragma unroll
    for (int e = 0; e < 4; e++) o[e] = f2bf((v[e] - mu) * rr * gf[e] + bf_[e]);
    uint2 ov;
    ov.x = (u32)o[0] | ((u32)o[1] << 16);
    ov.y = (u32)o[2] | ((u32)o[3] << 16);
    *(uint2*)(xn + (size_t)r * 256 + lane * 4) = ov;
}

// ------------- pairwise bias: bias[h][i][j] = LOG2E * sum_d pw[i][j][d]*we[d][h] -------------
// (log2-domain: attn kernel computes p = exp2(score) directly)
__global__ __launch_bounds__(256) void k_bias(
        const void* __restrict__ pw, const void* __restrict__ we,
        float* __restrict__ bias, const int* __restrict__ flagp) {
    const int flag = *flagp;
    __shared__ float swe[2048];  // [256][8] fp32
    for (int t = threadIdx.x; t < 2048; t += 256)
        swe[t] = flag ? ((const float*)we)[t] : bf2f(((const u16*)we)[t]);
    __syncthreads();
    const int i = blockIdx.x, j = threadIdx.x;
    const size_t rowoff = ((size_t)i * 256 + j) * 256;
    float acc[8] = {0.f, 0.f, 0.f, 0.f, 0.f, 0.f, 0.f, 0.f};
    for (int d0 = 0; d0 < 256; d0 += 8) {
        float f[8];
        if (flag) {
            const float* p32 = (const float*)pw + rowoff + d0;
            float4 a = *(const float4*)p32;
            float4 b = *(const float4*)(p32 + 4);
            f[0] = a.x; f[1] = a.y; f[2] = a.z; f[3] = a.w;
            f[4] = b.x; f[5] = b.y; f[6] = b.z; f[7] = b.w;
        } else {
            unpack8(*(const uint4*)((const u16*)pw + rowoff + d0), f);
        }
        #pragma unroll
        for (int e = 0; e < 8; e++) {
            const float* w = swe + (d0 + e) * 8;
            #pragma unroll
            for (int hh = 0; hh < 8; hh++) acc[hh] += f[e] * w[hh];
        }
    }
    #pragma unroll
    for (int hh = 0; hh < 8; hh++)
        bias[((size_t)hh * 256 + i) * 256 + j] = acc[hh] * 1.4426950408889634f;
}

// ---------------- MFMA GEMM: C[M,N] = A[M,256] @ Bt[N,256]^T ----------------
template<bool EPI, bool PERM, bool RESF, bool OUTF>
__global__ __launch_bounds__(256, 3) void k_gemm(
        const u16* __restrict__ A, const u16* __restrict__ Bt, void* __restrict__ C,
        size_t c_off, int N, const void* __restrict__ bias,
        const void* __restrict__ res, size_t res_off, int n0,
        const int* __restrict__ flagp) {
    constexpr int K = 256;
    const int flag = *flagp;
    __shared__ u16 sA[128 * 40];
    __shared__ u16 sB[128 * 40];
    const int tid = threadIdx.x;
    const int bm = blockIdx.x * 128, bn = blockIdx.y * 128;
    const int wave = tid >> 6, lane = tid & 63;
    const int wm = (wave >> 1) * 64, wn = (wave & 1) * 64;
    const int lr = lane & 15, lq = lane >> 4;
    f32x4 acc[4][4];
    #pragma unroll
    for (int a = 0; a < 4; a++)
        #pragma unroll
        for (int b2 = 0; b2 < 4; b2++) {
            acc[a][b2][0] = 0.f; acc[a][b2][1] = 0.f;
            acc[a][b2][2] = 0.f; acc[a][b2][3] = 0.f;
        }
    for (int k0 = 0; k0 < K; k0 += 32) {
        for (int c = tid; c < 512; c += 256) {
            int r = c >> 2, cc = (c & 3) << 3;
            *(uint4*)(sA + r * 40 + cc) = *(const uint4*)(A + (size_t)(bm + r) * K + k0 + cc);
            *(uint4*)(sB + r * 40 + cc) = *(const uint4*)(Bt + (size_t)(bn + r) * K + k0 + cc);
        }
        __syncthreads();
        bf16x8 af[4], bfr[4];
        #pragma unroll
        for (int t = 0; t < 4; t++) {
            af[t]  = *(const bf16x8*)(sA + (wm + t * 16 + lr) * 40 + lq * 8);
            bfr[t] = *(const bf16x8*)(sB + (wn + t * 16 + lr) * 40 + lq * 8);
        }
        #pragma unroll
        for (int mt = 0; mt < 4; mt++)
            #pragma unroll
            for (int nt = 0; nt < 4; nt++)
                acc[mt][nt] = __builtin_amdgcn_mfma_f32_16x16x32_bf16(
                        af[mt], bfr[nt], acc[mt][nt], 0, 0, 0);
        __syncthreads();
    }
    #pragma unroll
    for (int mt = 0; mt < 4; mt++)
        #pragma unroll
        for (int nt = 0; nt < 4; nt++)
            #pragma unroll
            for (int r = 0; r < 4; r++) {
                int row = bm + wm + mt * 16 + lq * 4 + r;
                int orow = PERM ? ((row & 127) * 256 + n0 + (row >> 7)) : row;
                int col = bn + wn + nt * 16 + lr;
                float v = acc[mt][nt][r];
                if (EPI) {
                    float bv = flag ? ((const float*)bias)[col] : bf2f(((const u16*)bias)[col]);
                    size_t ri = res_off + (size_t)orow * N + col;
                    float rv = (RESF && flag) ? ((const float*)res)[ri]
                                              : bf2f(((const u16*)res)[ri]);
                    v += bv + rv;
                }
                size_t ci = c_off + (size_t)orow * N + col;
                if (OUTF && flag) ((float*)C)[ci] = v;
                else ((u16*)C)[ci] = f2bf(v);
            }
}

// ---------------- MFMA flash attention (transposed-S) + output gating ----------------
// BASE = R7-exact structure (PASSED, 411.6us; R8's K-destaging REVERTED -- FETCH
// exploded 74->174MB: co-resident K working set ~32MB exceeds aggregate L2, K staging
// in LDS is load-bearing). Block = (head h, group b), L threads, wave owns 64 queries
// (4 tiles of 16). S^T = K·Q^T via MFMA(A=K,B=Q): C col=query=lr, row=key=lq*4+r.
// Q carries 1/sqrt(32)*log2(e); bias pre-scaled by log2(e): p = exp2(score), no max
// pass (fmin(v,80) guards; masked query -> p=1 uniform). P redistribution: cvt_pk +
// v_permlane32_swap + shfl_xor(16) + select (proven R3/R6). Batch-4 S-tiles.
// R9's ONLY change: 1-deep software pipeline on the bias loads (HB path) -- batch
// b4+1's 4 float4 loads issue before b4's exp/PV consume b4's bias, hiding the
// ~300-500cy L2/HBM latency under a full batch of MFMA+VALU work (R6/R7 issued them
// right before use; each of the 16 (b4,qt) iterations stalled on them).
template<bool HB, int L>
__global__ __launch_bounds__(L, 4) void k_attn_mfma(
        const u16* __restrict__ P, const float* __restrict__ bias,
        const int* __restrict__ mask, const void* __restrict__ bg,
        u16* __restrict__ out, int bstride, int mi_s, int mb_s, int m_base,
        const int* __restrict__ flagp) {
    constexpr int KT = L / 16;        // key tiles
    constexpr int NB = KT / 4;        // batches of 4 tiles (64 keys)
    constexpr int VROW = L + 8;       // svt row stride (halfwords)
    __shared__ u16 sk[L * 32];        // K rows [L][32], XOR-swizzled slots
    __shared__ u16 svt[32 * VROW];    // V^T [32][L]
    __shared__ float amk[L];          // additive key mask: 0 valid / -1e9 masked
    const int flag = *flagp;
    const int h = blockIdx.x, b = blockIdx.y;
    const int tid = threadIdx.x;
    constexpr float LOG2E = 1.4426950408889634f;

    // ---- stage K (raw copy, swizzled slots), V^T, additive mask ----
    {
        const size_t prow = (size_t)(b * bstride + tid) * 1024 + h * 32;
        const u16* kp = P + prow + 256;
        const int sw = (tid >> 1) & 3;
        #pragma unroll
        for (int c = 0; c < 4; c++)
            *(uint4*)(sk + tid * 32 + ((c ^ sw) << 3)) = *(const uint4*)(kp + c * 8);
        const u16* vp = P + prow + 512;
        #pragma unroll
        for (int c = 0; c < 4; c++) {
            uint4 d = *(const uint4*)(vp + c * 8);
            u16 hw[8];
            hw[0] = (u16)(d.x & 0xffffu); hw[1] = (u16)(d.x >> 16);
            hw[2] = (u16)(d.y & 0xffffu); hw[3] = (u16)(d.y >> 16);
            hw[4] = (u16)(d.z & 0xffffu); hw[5] = (u16)(d.z >> 16);
            hw[6] = (u16)(d.w & 0xffffu); hw[7] = (u16)(d.w >> 16);
            #pragma unroll
            for (int e = 0; e < 8; e++)
                svt[(c * 8 + e) * VROW + tid] = hw[e];
        }
        amk[tid] = (mask[tid * mi_s + b * mb_s + m_base] != 0) ? 0.f : -1e9f;
    }
    __syncthreads();

    const int wave = tid >> 6, lane = tid & 63;
    const int lq = lane >> 4, lr = lane & 15;
    const bool hi_lq = (lq & 1) != 0;
    const int qbase = wave * 64;

    // Q fragments: register layout identical for A and B operands (read [lr][lq*8..+8])
    bf16x8 qf[4];
    #pragma unroll
    for (int qt = 0; qt < 4; qt++) {
        const size_t qrow = (size_t)(b * bstride + qbase + qt * 16 + lr) * 1024 + h * 32;
        qf[qt] = *(const bf16x8*)(P + qrow + lq * 8);
    }
    float bgv[2];
    #pragma unroll
    for (int dt = 0; dt < 2; dt++)
        bgv[dt] = flag ? ((const float*)bg)[h * 32 + dt * 16 + lr]
                       : bf2f(((const u16*)bg)[h * 32 + dt * 16 + lr]);

    const f32x4 zero = {0.f, 0.f, 0.f, 0.f};
    #pragma unroll
    for (int qt = 0; qt < 4; qt++) {
        const float qv = amk[qbase + qt * 16 + lr];   // 0 = valid query, -1e9 = masked
        const bool qok = (qv == 0.f);
        const float* bp = HB ? (bias + ((size_t)(h * 256 + qbase + qt * 16 + lr)) * 256)
                             : nullptr;
        // gate prefetch (consumed only in the epilogue)
        const u16* gbase = P + (size_t)(b * bstride + qbase + qt * 16 + lq * 4) * 1024
                           + 768 + h * 32 + lr;
        u16 gpre[8];
        #pragma unroll
        for (int r = 0; r < 4; r++) {
            gpre[r * 2 + 0] = gbase[r * 1024];
            gpre[r * 2 + 1] = gbase[r * 1024 + 16];
        }
        float lsum = 0.f;
        f32x4 o0 = zero, o1 = zero;
        // ---- bias pipeline: prefetch batch 0 ----
        float4 bias_n[4];
        if (HB) {
            #pragma unroll
            for (int t = 0; t < 4; t++)
                bias_n[t] = *(const float4*)(bp + t * 16 + lq * 4);
        }
        #pragma unroll
        for (int b4 = 0; b4 < NB; b4++) {
            // consume prefetched bias; issue next batch's loads (hidden under MFMA+exp+PV)
            float4 bias4[4];
            if (HB) {
                #pragma unroll
                for (int t = 0; t < 4; t++) bias4[t] = bias_n[t];
                if (b4 + 1 < NB) {
                    #pragma unroll
                    for (int t = 0; t < 4; t++)
                        bias_n[t] = *(const float4*)(bp + ((b4 + 1) * 4 + t) * 16 + lq * 4);
                }
            }
            // ---- S^T: 4 tiles of 16 keys, back-to-back ----
            f32x4 s4[4];
            __builtin_amdgcn_s_setprio(1);
            #pragma unroll
            for (int t = 0; t < 4; t++) {
                const int rk = (b4 * 4 + t) * 16 + lr;
                bf16x8 ak = *(const bf16x8*)(sk + rk * 32 + ((lq ^ ((rk >> 1) & 3)) << 3));
                s4[t] = __builtin_amdgcn_mfma_f32_16x16x32_bf16(ak, qf[qt], zero, 0, 0, 0);
            }
            __builtin_amdgcn_s_setprio(0);
            // ---- per 32-key chunk: exp2 -> in-register redistribute -> PV MFMA ----
            #pragma unroll
            for (int cc = 0; cc < 2; cc++) {
                const int ch = b4 * 2 + cc;           // global chunk of 32 keys
                float p0[4], p1[4];
                #pragma unroll
                for (int t2 = 0; t2 < 2; t2++) {
                    const int t = 2 * cc + t2;
                    const int kt = b4 * 4 + t;
                    const float4 ka = *(const float4*)(amk + kt * 16 + lq * 4);
                    const float* kap = (const float*)&ka;
                    float* pp = t2 ? p1 : p0;
                    #pragma unroll
                    for (int r = 0; r < 4; r++) {
                        float v = s4[t][r] + kap[r];
                        if (HB) v += ((const float*)&bias4[t])[r];
                        v = qok ? fminf(v, 80.f) : 0.f;   // masked query: p=1 uniform
                        pp[r] = __builtin_amdgcn_exp2f(v);
                        lsum += pp[r];
                    }
                }
                // pack + 4-lane lq-permute, all in registers (PROVEN in R3)
                u32 y0 = cvtpk_bf16(p0[0], p0[1]);   // A of tile t2=0 (keys lq*4+0,1)
                u32 z0 = cvtpk_bf16(p0[2], p0[3]);   // B of tile t2=0 (keys lq*4+2,3)
                u32 y1 = cvtpk_bf16(p1[0], p1[1]);   // A of tile t2=1
                u32 z1 = cvtpk_bf16(p1[2], p1[3]);   // B of tile t2=1
                // half-swap: after this Y0 = A_{lq>>1}(lq&1), Y1 = A_{lq>>1}((lq&1)+2)
                asm("v_permlane32_swap_b32 %0, %1" : "+v"(y0), "+v"(y1));
                asm("v_permlane32_swap_b32 %0, %1" : "+v"(z0), "+v"(z1));
                const u32 sy0 = (u32)__shfl_xor((int)y0, 16, 64);
                const u32 sy1 = (u32)__shfl_xor((int)y1, 16, 64);
                const u32 sz0 = (u32)__shfl_xor((int)z0, 16, 64);
                const u32 sz1 = (u32)__shfl_xor((int)z1, 16, 64);
                u32x4 pu;
                pu.x = hi_lq ? sy1 : y0;   // keys 8lq+0,1
                pu.y = hi_lq ? sz1 : z0;   // keys 8lq+2,3
                pu.z = hi_lq ? y1 : sy0;   // keys 8lq+4,5
                pu.w = hi_lq ? z1 : sz0;   // keys 8lq+6,7
                const bf16x8 pa = __builtin_bit_cast(bf16x8, pu);
                bf16x8 vb0 = *(const bf16x8*)(svt + (size_t)lr * VROW + ch * 32 + lq * 8);
                bf16x8 vb1 = *(const bf16x8*)(svt + (size_t)(16 + lr) * VROW + ch * 32 + lq * 8);
                o0 = __builtin_amdgcn_mfma_f32_16x16x32_bf16(pa, vb0, o0, 0, 0, 0);
                o1 = __builtin_amdgcn_mfma_f32_16x16x32_bf16(pa, vb1, o1, 0, 0, 0);
            }
        }
        lsum += __shfl_xor(lsum, 16, 64);
        lsum += __shfl_xor(lsum, 32, 64);
        // ---- epilogue: 1/l, gate sigmoid, store (O rows = queries lq*4+r) ----
        #pragma unroll
        for (int r = 0; r < 4; r++) {
            const float lq_l = __shfl(lsum, (lane & 48) | (lq * 4 + r), 64);
            const float inv = __builtin_amdgcn_rcpf(lq_l);
            const size_t row = (size_t)(b * bstride + qbase + qt * 16 + lq * 4 + r);
            u16* op = out + row * 256 + h * 32;
            #pragma unroll
            for (int dt = 0; dt < 2; dt++) {
                const float ov = (dt ? o1[r] : o0[r]) * inv;
                const float g = bf2f(gpre[r * 2 + dt]) + bgv[dt];
                const float sig = __builtin_amdgcn_rcpf(1.f + __builtin_amdgcn_exp2f(-g * LOG2E));
                op[dt * 16 + lr] = f2bf(ov * sig);
            }
        }
    }
}

extern "C" void kernel_launch(void* const* d_in, const int* in_sizes, int n_in,
                              void* d_out, int out_size, void* d_ws, size_t ws_size,
                              hipStream_t stream) {
    (void)in_sizes; (void)n_in; (void)out_size;
    const void* x        = d_in[0];
    const void* pw       = d_in[1];
    const int*  mask     = (const int*)d_in[2];
    const void* row_ln_g = d_in[3];
    const void* row_ln_b = d_in[4];
    const void* row_wq   = d_in[5];
    const void* row_wkv  = d_in[6];
    const void* row_wg   = d_in[7];
    const void* row_bg   = d_in[8];
    const void* row_wo   = d_in[9];
    const void* row_bo   = d_in[10];
    const void* row_we   = d_in[11];
    const void* col_ln_g = d_in[12];
    const void* col_ln_b = d_in[13];
    const void* col_wq   = d_in[14];
    const void* col_wkv  = d_in[15];
    const void* col_wg   = d_in[16];
    const void* col_bg   = d_in[17];
    const void* col_wo   = d_in[18];
    const void* col_bo   = d_in[19];

    // 1/sqrt(32) * log2(e), folded into wq -> attn computes p = exp2(score)
    const float QSCALE = 0.17677669529663687f * 1.4426950408889634f;

    // choose chunking from ws_size (host-side, capture-stable):
    const int nc = (ws_size >= 120193536u) ? 1 : 8;
    const int rows = 32768 / nc;          // rows per chunk

    char* ws = (char*)d_ws;
    size_t off = 0;
    int*   flagp  = (int*)(ws + off);  off += 512;
    u16*   Wt     = (u16*)(ws + off);  off += 524288;      // [1024][256] bf16
    u16*   WoT    = (u16*)(ws + off);  off += 131072;      // [256][256] bf16
    float* biasb  = (float*)(ws + off); off += 2097152;    // [8][256][256] fp32
    u16*   xn_c   = (u16*)(ws + off);  off += (size_t)rows * 512;   // bf16
    u16*   attn_c = (u16*)(ws + off);  off += (size_t)rows * 512;   // bf16
    u16*   P_c    = (u16*)(ws + off);  off += (size_t)rows * 2048;  // bf16
    u16*   x1     = (u16*)(ws + off);  off += 16777216;    // [32768][256] bf16

    k_flag<<<1, 256, 0, stream>>>(x, flagp);

    // ---------------- stage 1: row attention (x1 in ws, bf16) ----------------
    k_tr4<<<1280, 256, 0, stream>>>(row_wq, row_wkv, row_wg, row_wo,
                                    Wt, WoT, flagp, QSCALE);
    k_bias<<<256, 256, 0, stream>>>(pw, row_we, biasb, flagp);
    for (int c = 0; c < nc; c++) {
        const int s0 = c * (128 / nc);    // first MSA row of chunk
        k_ln<<<rows / 4, 256, 0, stream>>>(x, row_ln_g, row_ln_b, xn_c,
                                           128, 1, s0 * 256, flagp, 1);
        k_gemm<false, false, false, false><<<dim3(rows / 128, 8), 256, 0, stream>>>(
                xn_c, Wt, P_c, 0, 1024, nullptr, nullptr, 0, 0, flagp);
        k_attn_mfma<true, 256><<<dim3(8, 128 / nc), 256, 0, stream>>>(
                P_c, biasb, mask, row_bg, attn_c, 256, 1, 256, s0 * 256, flagp);
        k_gemm<true, false, true, false><<<dim3(rows / 128, 2), 256, 0, stream>>>(
                attn_c, WoT, x1, (size_t)s0 * 65536, 256,
                row_bo, x, (size_t)s0 * 65536, 0, flagp);
    }

    // ---------------- stage 2: column attention (reads x1 bf16, writes d_out) ----------------
    k_tr4<<<1280, 256, 0, stream>>>(col_wq, col_wkv, col_wg, col_wo,
                                    Wt, WoT, flagp, QSCALE);
    for (int c = 0; c < nc; c++) {
        const int n0 = c * (256 / nc);    // first residue column of chunk
        k_ln<<<rows / 4, 256, 0, stream>>>(x1, col_ln_g, col_ln_b, xn_c,
                                           1, 256, n0, flagp, 0);
        k_gemm<false, false, false, false><<<dim3(rows / 128, 8), 256, 0, stream>>>(
                xn_c, Wt, P_c, 0, 1024, nullptr, nullptr, 0, 0, flagp);
        k_attn_mfma<false, 128><<<dim3(8, 256 / nc), 128, 0, stream>>>(
                P_c, nullptr, mask, col_bg, attn_c, 128, 256, 1, n0, flagp);
        k_gemm<true, true, false, true><<<dim3(rows / 128, 2), 256, 0, stream>>>(
                attn_c, WoT, d_out, 0, 256, col_bo, x1, 0, n0, flagp);
    }
}

// Round 10
// 399.279 us; speedup vs baseline: 1.1803x; 1.0547x over previous
//
#include <hip/hip_runtime.h>

typedef unsigned short u16;
typedef unsigned int u32;
typedef __bf16 bf16x8 __attribute__((ext_vector_type(8)));
typedef float f32x4 __attribute__((ext_vector_type(4)));
typedef u32 u32x4 __attribute__((ext_vector_type(4)));

__device__ __forceinline__ float bf2f(u16 u) {
    union { u32 u; float f; } x; x.u = ((u32)u) << 16; return x.f;
}
__device__ __forceinline__ u16 f2bf(float f) {
    union { float f; u32 u; } x; x.f = f;
    u32 r = x.u + 0x7fffu + ((x.u >> 16) & 1u);
    return (u16)(r >> 16);
}
__device__ __forceinline__ void unpack8(uint4 d, float* f) {
    f[0] = bf2f((u16)(d.x & 0xffffu)); f[1] = bf2f((u16)(d.x >> 16));
    f[2] = bf2f((u16)(d.y & 0xffffu)); f[3] = bf2f((u16)(d.y >> 16));
    f[4] = bf2f((u16)(d.z & 0xffffu)); f[5] = bf2f((u16)(d.z >> 16));
    f[6] = bf2f((u16)(d.w & 0xffffu)); f[7] = bf2f((u16)(d.w >> 16));
}
// pack 2 f32 -> u32 of 2 bf16 (RNE), single instruction; low half = first arg
__device__ __forceinline__ u32 cvtpk_bf16(float lo, float hi) {
    u32 r;
    asm("v_cvt_pk_bf16_f32 %0, %1, %2" : "=v"(r) : "v"(lo), "v"(hi));
    return r;
}
// async global->LDS 16B copy: per-lane global src, lane-linear LDS dest
__device__ __forceinline__ void gload_lds16(const u16* g, u16* l) {
    __builtin_amdgcn_global_load_lds(
        (const __attribute__((address_space(1))) void*)g,
        (__attribute__((address_space(3))) void*)l, 16, 0, 0);
}

// ---- dtype sniffing: fp32 data read as bf16 halfwords has wild exponents ----
__global__ __launch_bounds__(256) void k_flag(const void* __restrict__ x, int* __restrict__ flag) {
    const u16* p = (const u16*)x;
    const int t = threadIdx.x;
    float mx = 0.f;
    for (int i = t; i < 4096; i += 256) {
        float v = fabsf(bf2f(p[i]));
        if (!(v < 1e30f)) v = 1e30f;  // NaN/Inf -> big
        mx = fmaxf(mx, v);
    }
    __shared__ float red[256];
    red[t] = mx; __syncthreads();
    for (int s = 128; s > 0; s >>= 1) {
        if (t < s) red[t] = fmaxf(red[t], red[t + s]);
        __syncthreads();
    }
    if (t == 0) *flag = (red[0] > 1e6f) ? 1 : 0;  // 1 = fp32, 0 = bf16
}

// -------- fused weight transpose+convert for one attention stage --------
// Segments (1280 blocks): [0,256) wq*qscale -> Wt, [256,768) wkv -> Wt+65536,
// [768,1024) wg -> Wt+196608, [1024,1280) wo -> WoT. All K=256; Wt[n*256+k].
__global__ __launch_bounds__(256) void k_tr4(
        const void* __restrict__ W0, const void* __restrict__ W1,
        const void* __restrict__ W2, const void* __restrict__ W3,
        u16* __restrict__ Wt, u16* __restrict__ WoT,
        const int* __restrict__ flagp, float qscale) {
    const int flag = *flagp;
    const int blk = blockIdx.x;
    const void* W; u16* dst; int N; float scale = 1.f; int base;
    if (blk < 256)       { W = W0; dst = Wt;          N = 256; scale = qscale; base = 0; }
    else if (blk < 768)  { W = W1; dst = Wt + 65536;  N = 512; base = 256; }
    else if (blk < 1024) { W = W2; dst = Wt + 196608; N = 256; base = 768; }
    else                 { W = W3; dst = WoT;         N = 256; base = 1024; }
    const int idx = (blk - base) * 256 + threadIdx.x;
    const int k = idx / N, n = idx - k * N;
    float f = flag ? ((const float*)W)[idx] : bf2f(((const u16*)W)[idx]);
    dst[n * 256 + k] = f2bf(f * scale);
}

// ---------------- LayerNorm over D=256, one wave per local row ----------------
__global__ __launch_bounds__(256) void k_ln(
        const void* __restrict__ x, const void* __restrict__ g,
        const void* __restrict__ b, u16* __restrict__ xn,
        int so, int si, int base, const int* __restrict__ flagp, int xmode) {
    const int flag = *flagp;
    const int xf = xmode ? flag : 0;
    const int wave = threadIdx.x >> 6, lane = threadIdx.x & 63;
    const int r = blockIdx.x * 4 + wave;
    const int in_row = (r >> 7) * so + (r & 127) * si + base;
    const size_t off = (size_t)in_row * 256 + lane * 4;
    float v[4];
    if (xf) {
        float4 d = *(const float4*)((const float*)x + off);
        v[0] = d.x; v[1] = d.y; v[2] = d.z; v[3] = d.w;
    } else {
        uint2 d = *(const uint2*)((const u16*)x + off);
        v[0] = bf2f((u16)(d.x & 0xffffu)); v[1] = bf2f((u16)(d.x >> 16));
        v[2] = bf2f((u16)(d.y & 0xffffu)); v[3] = bf2f((u16)(d.y >> 16));
    }
    float s = v[0] + v[1] + v[2] + v[3];
    #pragma unroll
    for (int o2 = 32; o2 > 0; o2 >>= 1) s += __shfl_xor(s, o2, 64);
    float mu = s * (1.f / 256.f);
    float vs = 0.f;
    #pragma unroll
    for (int e = 0; e < 4; e++) { float t = v[e] - mu; vs += t * t; }
    #pragma unroll
    for (int o2 = 32; o2 > 0; o2 >>= 1) vs += __shfl_xor(vs, o2, 64);
    float rr = rsqrtf(vs * (1.f / 256.f) + 1e-5f);
    float gf[4], bf_[4];
    if (flag) {
        float4 gg = *(const float4*)((const float*)g + lane * 4);
        float4 bb = *(const float4*)((const float*)b + lane * 4);
        gf[0] = gg.x; gf[1] = gg.y; gf[2] = gg.z; gf[3] = gg.w;
        bf_[0] = bb.x; bf_[1] = bb.y; bf_[2] = bb.z; bf_[3] = bb.w;
    } else {
        uint2 gg = *(const uint2*)((const u16*)g + lane * 4);
        uint2 bb = *(const uint2*)((const u16*)b + lane * 4);
        gf[0] = bf2f((u16)(gg.x & 0xffffu)); gf[1] = bf2f((u16)(gg.x >> 16));
        gf[2] = bf2f((u16)(gg.y & 0xffffu)); gf[3] = bf2f((u16)(gg.y >> 16));
        bf_[0] = bf2f((u16)(bb.x & 0xffffu)); bf_[1] = bf2f((u16)(bb.x >> 16));
        bf_[2] = bf2f((u16)(bb.y & 0xffffu)); bf_[3] = bf2f((u16)(bb.y >> 16));
    }
    u16 o[4];
    #pragma unroll
    for (int e = 0; e < 4; e++) o[e] = f2bf((v[e] - mu) * rr * gf[e] + bf_[e]);
    uint2 ov;
    ov.x = (u32)o[0] | ((u32)o[1] << 16);
    ov.y = (u32)o[2] | ((u32)o[3] << 16);
    *(uint2*)(xn + (size_t)r * 256 + lane * 4) = ov;
}

// ------------- pairwise bias: bias[h][i][j] = LOG2E * sum_d pw[i][j][d]*we[d][h] -------------
// (log2-domain: attn kernel computes p = exp2(score) directly)
__global__ __launch_bounds__(256) void k_bias(
        const void* __restrict__ pw, const void* __restrict__ we,
        float* __restrict__ bias, const int* __restrict__ flagp) {
    const int flag = *flagp;
    __shared__ float swe[2048];  // [256][8] fp32
    for (int t = threadIdx.x; t < 2048; t += 256)
        swe[t] = flag ? ((const float*)we)[t] : bf2f(((const u16*)we)[t]);
    __syncthreads();
    const int i = blockIdx.x, j = threadIdx.x;
    const size_t rowoff = ((size_t)i * 256 + j) * 256;
    float acc[8] = {0.f, 0.f, 0.f, 0.f, 0.f, 0.f, 0.f, 0.f};
    for (int d0 = 0; d0 < 256; d0 += 8) {
        float f[8];
        if (flag) {
            const float* p32 = (const float*)pw + rowoff + d0;
            float4 a = *(const float4*)p32;
            float4 b = *(const float4*)(p32 + 4);
            f[0] = a.x; f[1] = a.y; f[2] = a.z; f[3] = a.w;
            f[4] = b.x; f[5] = b.y; f[6] = b.z; f[7] = b.w;
        } else {
            unpack8(*(const uint4*)((const u16*)pw + rowoff + d0), f);
        }
        #pragma unroll
        for (int e = 0; e < 8; e++) {
            const float* w = swe + (d0 + e) * 8;
            #pragma unroll
            for (int hh = 0; hh < 8; hh++) acc[hh] += f[e] * w[hh];
        }
    }
    #pragma unroll
    for (int hh = 0; hh < 8; hh++)
        bias[((size_t)hh * 256 + i) * 256 + j] = acc[hh] * 1.4426950408889634f;
}

// ---------------- MFMA GEMM: C[M,N] = A[M,256] @ Bt[N,256]^T ----------------
// R10: staging via global_load_lds width=16 (m193: the biggest GEMM lever).
// LDS is LINEAR [128][32] halfwords (gload_lds requires wave-uniform base +
// lane*16 dest -- no padding allowed, m173). Bank conflicts handled by XOR
// chunk swizzle sw(r) = (r + (r>>2)) & 3 applied to the GLOBAL source chunk
// (LDS stays linear; read side applies same XOR -> round-trips to identity).
// Read-side bank check: 16 lanes/lq-group land 2-way max (2-way free, m136).
template<bool EPI, bool PERM, bool RESF, bool OUTF>
__global__ __launch_bounds__(256, 3) void k_gemm(
        const u16* __restrict__ A, const u16* __restrict__ Bt, void* __restrict__ C,
        size_t c_off, int N, const void* __restrict__ bias,
        const void* __restrict__ res, size_t res_off, int n0,
        const int* __restrict__ flagp) {
    constexpr int K = 256;
    const int flag = *flagp;
    __shared__ u16 sA[128 * 32];
    __shared__ u16 sB[128 * 32];
    const int tid = threadIdx.x;
    const int bm = blockIdx.x * 128, bn = blockIdx.y * 128;
    const int wave = tid >> 6, lane = tid & 63;
    const int wm = (wave >> 1) * 64, wn = (wave & 1) * 64;
    const int lr = lane & 15, lq = lane >> 4;
    f32x4 acc[4][4];
    #pragma unroll
    for (int a = 0; a < 4; a++)
        #pragma unroll
        for (int b2 = 0; b2 < 4; b2++) {
            acc[a][b2][0] = 0.f; acc[a][b2][1] = 0.f;
            acc[a][b2][2] = 0.f; acc[a][b2][3] = 0.f;
        }
    for (int k0 = 0; k0 < K; k0 += 32) {
        #pragma unroll
        for (int i = 0; i < 2; i++) {
            const int c = i * 256 + tid;                 // lane-linear within wave
            const int r = c >> 2, ch = c & 3;
            const int sg = (ch ^ ((r + (r >> 2)) & 3)) << 3;  // swizzled src chunk
            gload_lds16(A  + (size_t)(bm + r) * K + k0 + sg, sA + c * 8);
            gload_lds16(Bt + (size_t)(bn + r) * K + k0 + sg, sB + c * 8);
        }
        __syncthreads();
        bf16x8 af[4], bfr[4];
        #pragma unroll
        for (int t = 0; t < 4; t++) {
            const int ra = wm + t * 16 + lr;
            const int rb = wn + t * 16 + lr;
            af[t]  = *(const bf16x8*)(sA + ra * 32 + ((lq ^ ((ra + (ra >> 2)) & 3)) << 3));
            bfr[t] = *(const bf16x8*)(sB + rb * 32 + ((lq ^ ((rb + (rb >> 2)) & 3)) << 3));
        }
        #pragma unroll
        for (int mt = 0; mt < 4; mt++)
            #pragma unroll
            for (int nt = 0; nt < 4; nt++)
                acc[mt][nt] = __builtin_amdgcn_mfma_f32_16x16x32_bf16(
                        af[mt], bfr[nt], acc[mt][nt], 0, 0, 0);
        __syncthreads();
    }
    #pragma unroll
    for (int mt = 0; mt < 4; mt++)
        #pragma unroll
        for (int nt = 0; nt < 4; nt++)
            #pragma unroll
            for (int r = 0; r < 4; r++) {
                int row = bm + wm + mt * 16 + lq * 4 + r;
                int orow = PERM ? ((row & 127) * 256 + n0 + (row >> 7)) : row;
                int col = bn + wn + nt * 16 + lr;
                float v = acc[mt][nt][r];
                if (EPI) {
                    float bv = flag ? ((const float*)bias)[col] : bf2f(((const u16*)bias)[col]);
                    size_t ri = res_off + (size_t)orow * N + col;
                    float rv = (RESF && flag) ? ((const float*)res)[ri]
                                              : bf2f(((const u16*)res)[ri]);
                    v += bv + rv;
                }
                size_t ci = c_off + (size_t)orow * N + col;
                if (OUTF && flag) ((float*)C)[ci] = v;
                else ((u16*)C)[ci] = f2bf(v);
            }
}

// ---------------- MFMA flash attention (transposed-S) + output gating ----------------
// R6/R7-EXACT (best passing config: 411.6us total, row-attn 61us). R9's bias
// pipeline REVERTED: +16 live VGPRs at the allocator's fixed 64-reg choice spilled
// (WRITE 29.7->35MB, row-attn 61->81us). Lesson: on this kernel, added live state
// converts directly to scratch; the ~13MB residual spill (~3 regs x 4qt) is the floor.
// Block = (head h, group b), L threads, wave owns 64 queries (4 tiles of 16).
// S^T = K·Q^T via MFMA(A=K,B=Q): C col=query=lr, row=key=lq*4+r. Q carries
// 1/sqrt(32)*log2(e); bias pre-scaled by log2(e): p = exp2(score), no max pass
// (fmin(v,80) guards; masked query -> p=1 uniform). P redistribution: cvt_pk +
// v_permlane32_swap + shfl_xor(16) + select (proven R3/R6). Batch-4 S-tiles.
template<bool HB, int L>
__global__ __launch_bounds__(L, 4) void k_attn_mfma(
        const u16* __restrict__ P, const float* __restrict__ bias,
        const int* __restrict__ mask, const void* __restrict__ bg,
        u16* __restrict__ out, int bstride, int mi_s, int mb_s, int m_base,
        const int* __restrict__ flagp) {
    constexpr int KT = L / 16;        // key tiles
    constexpr int NB = KT / 4;        // batches of 4 tiles (64 keys)
    constexpr int VROW = L + 8;       // svt row stride (halfwords)
    __shared__ u16 sk[L * 32];        // K rows [L][32], XOR-swizzled slots
    __shared__ u16 svt[32 * VROW];    // V^T [32][L]
    __shared__ float amk[L];          // additive key mask: 0 valid / -1e9 masked
    const int flag = *flagp;
    const int h = blockIdx.x, b = blockIdx.y;
    const int tid = threadIdx.x;
    constexpr float LOG2E = 1.4426950408889634f;

    // ---- stage K (raw copy, swizzled slots), V^T, additive mask ----
    {
        const size_t prow = (size_t)(b * bstride + tid) * 1024 + h * 32;
        const u16* kp = P + prow + 256;
        const int sw = (tid >> 1) & 3;
        #pragma unroll
        for (int c = 0; c < 4; c++)
            *(uint4*)(sk + tid * 32 + ((c ^ sw) << 3)) = *(const uint4*)(kp + c * 8);
        const u16* vp = P + prow + 512;
        #pragma unroll
        for (int c = 0; c < 4; c++) {
            uint4 d = *(const uint4*)(vp + c * 8);
            u16 hw[8];
            hw[0] = (u16)(d.x & 0xffffu); hw[1] = (u16)(d.x >> 16);
            hw[2] = (u16)(d.y & 0xffffu); hw[3] = (u16)(d.y >> 16);
            hw[4] = (u16)(d.z & 0xffffu); hw[5] = (u16)(d.z >> 16);
            hw[6] = (u16)(d.w & 0xffffu); hw[7] = (u16)(d.w >> 16);
            #pragma unroll
            for (int e = 0; e < 8; e++)
                svt[(c * 8 + e) * VROW + tid] = hw[e];
        }
        amk[tid] = (mask[tid * mi_s + b * mb_s + m_base] != 0) ? 0.f : -1e9f;
    }
    __syncthreads();

    const int wave = tid >> 6, lane = tid & 63;
    const int lq = lane >> 4, lr = lane & 15;
    const bool hi_lq = (lq & 1) != 0;
    const int qbase = wave * 64;

    // Q fragments: register layout identical for A and B operands (read [lr][lq*8..+8])
    bf16x8 qf[4];
    #pragma unroll
    for (int qt = 0; qt < 4; qt++) {
        const size_t qrow = (size_t)(b * bstride + qbase + qt * 16 + lr) * 1024 + h * 32;
        qf[qt] = *(const bf16x8*)(P + qrow + lq * 8);
    }
    float bgv[2];
    #pragma unroll
    for (int dt = 0; dt < 2; dt++)
        bgv[dt] = flag ? ((const float*)bg)[h * 32 + dt * 16 + lr]
                       : bf2f(((const u16*)bg)[h * 32 + dt * 16 + lr]);

    const f32x4 zero = {0.f, 0.f, 0.f, 0.f};
    #pragma unroll
    for (int qt = 0; qt < 4; qt++) {
        const float qv = amk[qbase + qt * 16 + lr];   // 0 = valid query, -1e9 = masked
        const bool qok = (qv == 0.f);
        const float* bp = HB ? (bias + ((size_t)(h * 256 + qbase + qt * 16 + lr)) * 256)
                             : nullptr;
        // gate prefetch (consumed only in the epilogue)
        const u16* gbase = P + (size_t)(b * bstride + qbase + qt * 16 + lq * 4) * 1024
                           + 768 + h * 32 + lr;
        u16 gpre[8];
        #pragma unroll
        for (int r = 0; r < 4; r++) {
            gpre[r * 2 + 0] = gbase[r * 1024];
            gpre[r * 2 + 1] = gbase[r * 1024 + 16];
        }
        float lsum = 0.f;
        f32x4 o0 = zero, o1 = zero;
        #pragma unroll
        for (int b4 = 0; b4 < NB; b4++) {
            // ---- batched bias loads (overlap the MFMA burst) ----
            float4 bias4[4];
            if (HB) {
                #pragma unroll
                for (int t = 0; t < 4; t++)
                    bias4[t] = *(const float4*)(bp + (b4 * 4 + t) * 16 + lq * 4);
            }
            // ---- S^T: 4 tiles of 16 keys, back-to-back ----
            f32x4 s4[4];
            __builtin_amdgcn_s_setprio(1);
            #pragma unroll
            for (int t = 0; t < 4; t++) {
                const int rk = (b4 * 4 + t) * 16 + lr;
                bf16x8 ak = *(const bf16x8*)(sk + rk * 32 + ((lq ^ ((rk >> 1) & 3)) << 3));
                s4[t] = __builtin_amdgcn_mfma_f32_16x16x32_bf16(ak, qf[qt], zero, 0, 0, 0);
            }
            __builtin_amdgcn_s_setprio(0);
            // ---- per 32-key chunk: exp2 -> in-register redistribute -> PV MFMA ----
            #pragma unroll
            for (int cc = 0; cc < 2; cc++) {
                const int ch = b4 * 2 + cc;           // global chunk of 32 keys
                float p0[4], p1[4];
                #pragma unroll
                for (int t2 = 0; t2 < 2; t2++) {
                    const int t = 2 * cc + t2;
                    const int kt = b4 * 4 + t;
                    const float4 ka = *(const float4*)(amk + kt * 16 + lq * 4);
                    const float* kap = (const float*)&ka;
                    float* pp = t2 ? p1 : p0;
                    #pragma unroll
                    for (int r = 0; r < 4; r++) {
                        float v = s4[t][r] + kap[r];
                        if (HB) v += ((const float*)&bias4[t])[r];
                        v = qok ? fminf(v, 80.f) : 0.f;   // masked query: p=1 uniform
                        pp[r] = __builtin_amdgcn_exp2f(v);
                        lsum += pp[r];
                    }
                }
                // pack + 4-lane lq-permute, all in registers (PROVEN in R3)
                u32 y0 = cvtpk_bf16(p0[0], p0[1]);   // A of tile t2=0 (keys lq*4+0,1)
                u32 z0 = cvtpk_bf16(p0[2], p0[3]);   // B of tile t2=0 (keys lq*4+2,3)
                u32 y1 = cvtpk_bf16(p1[0], p1[1]);   // A of tile t2=1
                u32 z1 = cvtpk_bf16(p1[2], p1[3]);   // B of tile t2=1
                // half-swap: after this Y0 = A_{lq>>1}(lq&1), Y1 = A_{lq>>1}((lq&1)+2)
                asm("v_permlane32_swap_b32 %0, %1" : "+v"(y0), "+v"(y1));
                asm("v_permlane32_swap_b32 %0, %1" : "+v"(z0), "+v"(z1));
                const u32 sy0 = (u32)__shfl_xor((int)y0, 16, 64);
                const u32 sy1 = (u32)__shfl_xor((int)y1, 16, 64);
                const u32 sz0 = (u32)__shfl_xor((int)z0, 16, 64);
                const u32 sz1 = (u32)__shfl_xor((int)z1, 16, 64);
                u32x4 pu;
                pu.x = hi_lq ? sy1 : y0;   // keys 8lq+0,1
                pu.y = hi_lq ? sz1 : z0;   // keys 8lq+2,3
                pu.z = hi_lq ? y1 : sy0;   // keys 8lq+4,5
                pu.w = hi_lq ? z1 : sz0;   // keys 8lq+6,7
                const bf16x8 pa = __builtin_bit_cast(bf16x8, pu);
                bf16x8 vb0 = *(const bf16x8*)(svt + (size_t)lr * VROW + ch * 32 + lq * 8);
                bf16x8 vb1 = *(const bf16x8*)(svt + (size_t)(16 + lr) * VROW + ch * 32 + lq * 8);
                o0 = __builtin_amdgcn_mfma_f32_16x16x32_bf16(pa, vb0, o0, 0, 0, 0);
                o1 = __builtin_amdgcn_mfma_f32_16x16x32_bf16(pa, vb1, o1, 0, 0, 0);
            }
        }
        lsum += __shfl_xor(lsum, 16, 64);
        lsum += __shfl_xor(lsum, 32, 64);
        // ---- epilogue: 1/l, gate sigmoid, store (O rows = queries lq*4+r) ----
        #pragma unroll
        for (int r = 0; r < 4; r++) {
            const float lq_l = __shfl(lsum, (lane & 48) | (lq * 4 + r), 64);
            const float inv = __builtin_amdgcn_rcpf(lq_l);
            const size_t row = (size_t)(b * bstride + qbase + qt * 16 + lq * 4 + r);
            u16* op = out + row * 256 + h * 32;
            #pragma unroll
            for (int dt = 0; dt < 2; dt++) {
                const float ov = (dt ? o1[r] : o0[r]) * inv;
                const float g = bf2f(gpre[r * 2 + dt]) + bgv[dt];
                const float sig = __builtin_amdgcn_rcpf(1.f + __builtin_amdgcn_exp2f(-g * LOG2E));
                op[dt * 16 + lr] = f2bf(ov * sig);
            }
        }
    }
}

extern "C" void kernel_launch(void* const* d_in, const int* in_sizes, int n_in,
                              void* d_out, int out_size, void* d_ws, size_t ws_size,
                              hipStream_t stream) {
    (void)in_sizes; (void)n_in; (void)out_size;
    const void* x        = d_in[0];
    const void* pw       = d_in[1];
    const int*  mask     = (const int*)d_in[2];
    const void* row_ln_g = d_in[3];
    const void* row_ln_b = d_in[4];
    const void* row_wq   = d_in[5];
    const void* row_wkv  = d_in[6];
    const void* row_wg   = d_in[7];
    const void* row_bg   = d_in[8];
    const void* row_wo   = d_in[9];
    const void* row_bo   = d_in[10];
    const void* row_we   = d_in[11];
    const void* col_ln_g = d_in[12];
    const void* col_ln_b = d_in[13];
    const void* col_wq   = d_in[14];
    const void* col_wkv  = d_in[15];
    const void* col_wg   = d_in[16];
    const void* col_bg   = d_in[17];
    const void* col_wo   = d_in[18];
    const void* col_bo   = d_in[19];

    // 1/sqrt(32) * log2(e), folded into wq -> attn computes p = exp2(score)
    const float QSCALE = 0.17677669529663687f * 1.4426950408889634f;

    // choose chunking from ws_size (host-side, capture-stable):
    const int nc = (ws_size >= 120193536u) ? 1 : 8;
    const int rows = 32768 / nc;          // rows per chunk

    char* ws = (char*)d_ws;
    size_t off = 0;
    int*   flagp  = (int*)(ws + off);  off += 512;
    u16*   Wt     = (u16*)(ws + off);  off += 524288;      // [1024][256] bf16
    u16*   WoT    = (u16*)(ws + off);  off += 131072;      // [256][256] bf16
    float* biasb  = (float*)(ws + off); off += 2097152;    // [8][256][256] fp32
    u16*   xn_c   = (u16*)(ws + off);  off += (size_t)rows * 512;   // bf16
    u16*   attn_c = (u16*)(ws + off);  off += (size_t)rows * 512;   // bf16
    u16*   P_c    = (u16*)(ws + off);  off += (size_t)rows * 2048;  // bf16
    u16*   x1     = (u16*)(ws + off);  off += 16777216;    // [32768][256] bf16

    k_flag<<<1, 256, 0, stream>>>(x, flagp);

    // ---------------- stage 1: row attention (x1 in ws, bf16) ----------------
    k_tr4<<<1280, 256, 0, stream>>>(row_wq, row_wkv, row_wg, row_wo,
                                    Wt, WoT, flagp, QSCALE);
    k_bias<<<256, 256, 0, stream>>>(pw, row_we, biasb, flagp);
    for (int c = 0; c < nc; c++) {
        const int s0 = c * (128 / nc);    // first MSA row of chunk
        k_ln<<<rows / 4, 256, 0, stream>>>(x, row_ln_g, row_ln_b, xn_c,
                                           128, 1, s0 * 256, flagp, 1);
        k_gemm<false, false, false, false><<<dim3(rows / 128, 8), 256, 0, stream>>>(
                xn_c, Wt, P_c, 0, 1024, nullptr, nullptr, 0, 0, flagp);
        k_attn_mfma<true, 256><<<dim3(8, 128 / nc), 256, 0, stream>>>(
                P_c, biasb, mask, row_bg, attn_c, 256, 1, 256, s0 * 256, flagp);
        k_gemm<true, false, true, false><<<dim3(rows / 128, 2), 256, 0, stream>>>(
                attn_c, WoT, x1, (size_t)s0 * 65536, 256,
                row_bo, x, (size_t)s0 * 65536, 0, flagp);
    }

    // ---------------- stage 2: column attention (reads x1 bf16, writes d_out) ----------------
    k_tr4<<<1280, 256, 0, stream>>>(col_wq, col_wkv, col_wg, col_wo,
                                    Wt, WoT, flagp, QSCALE);
    for (int c = 0; c < nc; c++) {
        const int n0 = c * (256 / nc);    // first residue column of chunk
        k_ln<<<rows / 4, 256, 0, stream>>>(x1, col_ln_g, col_ln_b, xn_c,
                                           1, 256, n0, flagp, 0);
        k_gemm<false, false, false, false><<<dim3(rows / 128, 8), 256, 0, stream>>>(
                xn_c, Wt, P_c, 0, 1024, nullptr, nullptr, 0, 0, flagp);
        k_attn_mfma<false, 128><<<dim3(8, 256 / nc), 128, 0, stream>>>(
                P_c, nullptr, mask, col_bg, attn_c, 128, 256, 1, n0, flagp);
        k_gemm<true, true, false, true><<<dim3(rows / 128, 2), 256, 0, stream>>>(
                attn_c, WoT, d_out, 0, 256, col_bo, x1, 0, n0, flagp);
    }
}